// Round 18
// baseline (158.623 us; speedup 1.0000x reference)
//
#include <hip/hip_runtime.h>
#include <math.h>

#define DEVI __device__ __forceinline__

using bf16x8 = __attribute__((ext_vector_type(8))) short;
using f32x4  = __attribute__((ext_vector_type(4))) float;

DEVI float b2f(unsigned short u) {
  union { unsigned int u; float f; } x; x.u = ((unsigned int)u) << 16; return x.f;
}
DEVI unsigned short f2b(float f) {
  union { float f; unsigned int u; } x; x.f = f;
  unsigned int r = (x.u + 0x7fffu + ((x.u >> 16) & 1u)) >> 16;
  return (unsigned short)r;
}
DEVI float gelu_f(float x) { return 0.5f * x * (1.0f + erff(x * 0.70710678118654752440f)); }

DEVI void wredxor2(float& a, float& b) {
  #pragma unroll
  for (int off = 32; off; off >>= 1) {
    a += __shfl_xor(a, off);
    b += __shfl_xor(b, off);
  }
}

template<int NW>
DEVI void breduce2(float& a, float& b) {
  __shared__ float buf[2 * NW];
  int lane = threadIdx.x & 63;
  int w = threadIdx.x >> 6;
  #pragma unroll
  for (int off = 32; off > 0; off >>= 1) {
    a += __shfl_down(a, off);
    b += __shfl_down(b, off);
  }
  if (lane == 0) { buf[w] = a; buf[NW + w] = b; }
  __syncthreads();
  float ra = 0.f, rb = 0.f;
  #pragma unroll
  for (int i = 0; i < NW; ++i) { ra += buf[i]; rb += buf[NW + i]; }
  a = ra; b = rb;
  __syncthreads();
}

DEVI void span_params(const int* st, const int* en, int span,
                      int& s, int& e, int& left, int& right) {
  int s0 = st[span], e0 = en[span];
  s = min(max(s0, 0), 511);
  e = max(s, min(e0, 511));
  left = max(0, s - 3);
  right = min(512, e + 4);
}

// bijective XCD chunk transform (m204)
DEVI int xcd_logical(int bid, int n) {
  int q = n >> 3, r = n & 7;
  int xcd = bid & 7, idx = bid >> 3;
  return (xcd < r ? xcd * (q + 1) : r * (q + 1) + (xcd - r) * q) + idx;
}

// ---------------- fused prep ----------------
__global__ __launch_bounds__(256) void prep_kernel(
    const float* __restrict__ w1, const float* __restrict__ w_in,
    const float* __restrict__ w_out, const float* __restrict__ fus_w,
    const float* __restrict__ sen_w1, const float* __restrict__ fus_b,
    const float* __restrict__ b_out,
    unsigned short* __restrict__ w1b, unsigned short* __restrict__ winb,
    unsigned short* __restrict__ Wbig, unsigned short* __restrict__ fusbR,
    unsigned short* __restrict__ senb, unsigned short* __restrict__ w_outT,
    float* __restrict__ bias2,
    const float* __restrict__ seq, const float* __restrict__ ate_g,
    const float* __restrict__ ate_b, unsigned short* __restrict__ sbf,
    float2* __restrict__ stats, float2* __restrict__ c12,
    const int* __restrict__ st, const int* __restrict__ en,
    int* __restrict__ tokmap) {
  __shared__ unsigned short ldsT[8 * 776];      // 12.4 KB (occupancy-safe)
  const int bid = blockIdx.x, tid = threadIdx.x;
  if (bid < 3456) {
    int i = bid * 256 + tid;
    if (i < 73728) {
      float4 v = reinterpret_cast<const float4*>(w1)[i];
      int k0 = (i * 4) % 768;
      float4 gv = *reinterpret_cast<const float4*>(ate_g + k0);
      ushort4 o;
      o.x = f2b(v.x * gv.x); o.y = f2b(v.y * gv.y);
      o.z = f2b(v.z * gv.z); o.w = f2b(v.w * gv.w);
      reinterpret_cast<ushort4*>(w1b)[i] = o;
      return;
    }
    if (i < 516096) {
      int j = i - 73728;
      float4 v = reinterpret_cast<const float4*>(w_in)[j];
      ushort4 o;
      o.x = f2b(v.x); o.y = f2b(v.y); o.z = f2b(v.z); o.w = f2b(v.w);
      reinterpret_cast<ushort4*>(winb)[j] = o;
      return;
    }
    if (i < 811008) {
      int j = i - 516096;                  // float4 idx in fus_w [768][1536]
      float4 v = reinterpret_cast<const float4*>(fus_w)[j];
      ushort4 o;
      o.x = f2b(v.x); o.y = f2b(v.y); o.z = f2b(v.z); o.w = f2b(v.w);
      int row = j / 384, col4 = j % 384;
      if (col4 < 192)
        reinterpret_cast<ushort4*>(Wbig)[row * 384 + col4] = o;      // left half
      else
        reinterpret_cast<ushort4*>(fusbR)[row * 192 + (col4 - 192)] = o;
      return;
    }
    int j = i - 811008;
    float4 v = reinterpret_cast<const float4*>(sen_w1)[j];
    ushort4 o;
    o.x = f2b(v.x); o.y = f2b(v.y); o.z = f2b(v.z); o.w = f2b(v.w);
    reinterpret_cast<ushort4*>(senb)[j] = o;
  } else if (bid < 11648) {
    const int row = (bid - 3456) * 4 + (tid >> 6);
    const int lane = tid & 63;
    const float4* xr = reinterpret_cast<const float4*>(seq + (size_t)row * 768);
    float4 v[3];
    #pragma unroll
    for (int j = 0; j < 3; ++j) v[j] = xr[j * 64 + lane];
    float s = 0.f, q = 0.f;
    #pragma unroll
    for (int j = 0; j < 3; ++j) {
      s += v[j].x + v[j].y + v[j].z + v[j].w;
      q += v[j].x * v[j].x + v[j].y * v[j].y + v[j].z * v[j].z + v[j].w * v[j].w;
    }
    wredxor2(s, q);
    float mean = s * (1.0f / 768.0f);
    float rstd = rsqrtf(q * (1.0f / 768.0f) - mean * mean + 1e-5f);
    ushort4* orow = reinterpret_cast<ushort4*>(sbf + (size_t)row * 768);
    #pragma unroll
    for (int j = 0; j < 3; ++j) {
      ushort4 o;
      o.x = f2b(v[j].x); o.y = f2b(v[j].y); o.z = f2b(v[j].z); o.w = f2b(v[j].w);
      orow[j * 64 + lane] = o;
    }
    if (lane == 0) stats[row] = make_float2(rstd, rstd * mean);
  } else if (bid < 11744) {
    const int lane = tid & 63;
    const int j = (bid - 11648) * 4 + (tid >> 6);
    const float4* wr = reinterpret_cast<const float4*>(w1 + (size_t)j * 768);
    const float4* gp = reinterpret_cast<const float4*>(ate_g);
    const float4* bp = reinterpret_cast<const float4*>(ate_b);
    float a = 0.f, bsum = 0.f;
    #pragma unroll
    for (int i = 0; i < 3; ++i) {
      float4 wv = wr[i * 64 + lane];
      float4 gv = gp[i * 64 + lane];
      float4 bv = bp[i * 64 + lane];
      a    += gv.x * wv.x + gv.y * wv.y + gv.z * wv.z + gv.w * wv.w;
      bsum += bv.x * wv.x + bv.y * wv.y + bv.z * wv.z + bv.w * wv.w;
    }
    wredxor2(a, bsum);
    if (lane == 0) c12[j] = make_float2(a, bsum);
  } else if (bid < 11936) {
    // bias2[o] = fus_b[o] + sum_k fus_w[o][768+k] * b_out[k]
    const int lane = tid & 63;
    const int o = (bid - 11744) * 4 + (tid >> 6);
    const float4* wr = reinterpret_cast<const float4*>(fus_w + (size_t)o * 1536 + 768);
    const float4* bp = reinterpret_cast<const float4*>(b_out);
    float a = 0.f, dummy = 0.f;
    #pragma unroll
    for (int i = 0; i < 3; ++i) {
      float4 wv = wr[i * 64 + lane];
      float4 bv = bp[i * 64 + lane];
      a += wv.x * bv.x + wv.y * bv.y + wv.z * bv.z + wv.w * bv.w;
    }
    wredxor2(a, dummy);
    if (lane == 0) bias2[o] = fus_b[o] + a;
  } else if (bid < 12032) {
    // transpose 8-col stripe of w_out -> w_outT rows
    const int c0 = (bid - 11936) * 8;
    #pragma unroll
    for (int it = 0; it < 24; ++it) {
      int j = it * 32 + (tid >> 3);
      int c = tid & 7;
      ldsT[c * 776 + j] = f2b(w_out[(size_t)j * 768 + c0 + c]);
    }
    __syncthreads();
    #pragma unroll
    for (int c = 0; c < 8; ++c) {
      for (int u = tid; u < 768; u += 256)
        w_outT[(size_t)(c0 + c) * 768 + u] = ldsT[c * 776 + u];
    }
  } else {
    for (int i = tid; i < 3840; i += 256) {
      int span = i / 15, w = i % 15;
      int s, e, left, right;
      span_params(st, en, span, s, e, left, right);
      int b = span >> 2;
      tokmap[i] = b * 512 + min(left + w, 511);
    }
  }
}

// ---------------- MFMA bf16 GEMM core: BK=64, XOR-swizzled LDS ----------------
// T3-minimum pipeline: LDS double-buffer; stage(t+1) issued BEFORE compute(t);
// ONE __syncthreads() per K-step (drains next-tile loads after they were hidden
// under the current tile's ds_read+MFMA; also orders the buffer overwrite).
template<int BM, int BN, int WM, int WN>
DEVI void gemm_core(const unsigned short* __restrict__ A,
                    const unsigned short* __restrict__ W,
                    int K, int bm, int bn,
                    unsigned short* As, unsigned short* Bs,   // dbuf bases (2x)
                    f32x4 (&acc)[WM / 16][WN / 16],
                    const int* __restrict__ rowmap = nullptr) {
  constexpr int TA = BM * 64;
  constexpr int TB = BN * 64;
  constexpr int CA = BM / 8;
  constexpr int CB = BN / 8;
  constexpr int NWC = BN / WN;
  constexpr int WAVES = (BM / WM) * NWC;
  constexpr int CPA = CA / WAVES;
  constexpr int CPB = CB / WAVES;
  constexpr int FM = WM / 16, FN = WN / 16;
  const int tid = threadIdx.x;
  const int lane = tid & 63;
  const int wv = tid >> 6;
  const int wr = wv / NWC, wc = wv % NWC;
  const int l16 = lane & 15, lhi = lane >> 4;
  const int srow = lane >> 3;
  const int scol = 8 * ((lane & 7) ^ srow);

  size_t aoff[CPA], boff[CPB];
  #pragma unroll
  for (int c = 0; c < CPA; ++c) {
    int ar = bm + (wv + c * WAVES) * 8 + srow;
    aoff[c] = (rowmap ? (size_t)rowmap[ar] : (size_t)ar) * K + scol;
  }
  #pragma unroll
  for (int c = 0; c < CPB; ++c)
    boff[c] = (size_t)(bn + (wv + c * WAVES) * 8 + srow) * K + scol;

  auto stage = [&](int buf, int k0) {
    #pragma unroll
    for (int c = 0; c < CPA; ++c)
      __builtin_amdgcn_global_load_lds(
          (const __attribute__((address_space(1))) void*)&A[aoff[c] + k0],
          (__attribute__((address_space(3))) void*)&As[buf * TA + (wv + c * WAVES) * 512], 16, 0, 0);
    #pragma unroll
    for (int c = 0; c < CPB; ++c)
      __builtin_amdgcn_global_load_lds(
          (const __attribute__((address_space(1))) void*)&W[boff[c] + k0],
          (__attribute__((address_space(3))) void*)&Bs[buf * TB + (wv + c * WAVES) * 512], 16, 0, 0);
  };

  const int nt = K / 64;
  stage(0, 0);
  __syncthreads();
  int cur = 0;
  for (int t = 0; t < nt; ++t) {
    if (t + 1 < nt) stage(cur ^ 1, (t + 1) * 64);   // prefetch next tile (in flight under compute)
    #pragma unroll
    for (int kk = 0; kk < 2; ++kk) {
      bf16x8 af[FM], bfr[FN];
      #pragma unroll
      for (int fm = 0; fm < FM; ++fm) {
        int r = wr * WM + fm * 16 + l16;
        af[fm] = *reinterpret_cast<const bf16x8*>(&As[cur * TA + r * 64 + ((kk * 32 + lhi * 8) ^ ((r & 7) * 8))]);
      }
      #pragma unroll
      for (int fn = 0; fn < FN; ++fn) {
        int r = wc * WN + fn * 16 + l16;
        bfr[fn] = *reinterpret_cast<const bf16x8*>(&Bs[cur * TB + r * 64 + ((kk * 32 + lhi * 8) ^ ((r & 7) * 8))]);
      }
      __builtin_amdgcn_s_setprio(1);
      #pragma unroll
      for (int fm = 0; fm < FM; ++fm)
        #pragma unroll
        for (int fn = 0; fn < FN; ++fn)
          acc[fm][fn] = __builtin_amdgcn_mfma_f32_16x16x32_bf16(af[fm], bfr[fn], acc[fm][fn], 0, 0, 0);
      __builtin_amdgcn_s_setprio(0);
    }
    __syncthreads();     // drains next-tile loads (mostly arrived) + overwrite ordering
    cur ^= 1;
  }
}

// standard epilogue: bias (+gelu) -> bf16 store (NSTRIDE = C row stride; bias may be null)
template<int BM, int BN, int WM, int WN>
DEVI void gemm_store(const float* __restrict__ bias, unsigned short* __restrict__ C,
                     int NSTRIDE, bool act, int bm, int bn, f32x4 (&acc)[WM / 16][WN / 16]) {
  constexpr int NWC = BN / WN;
  constexpr int FM = WM / 16, FN = WN / 16;
  const int lane = threadIdx.x & 63;
  const int wv = threadIdx.x >> 6;
  const int wr = wv / NWC, wc = wv % NWC;
  const int l16 = lane & 15, lhi = lane >> 4;
  #pragma unroll
  for (int fm = 0; fm < FM; ++fm) {
    #pragma unroll
    for (int fn = 0; fn < FN; ++fn) {
      int col = bn + wc * WN + fn * 16 + l16;
      float bv = bias ? bias[col] : 0.f;
      #pragma unroll
      for (int i = 0; i < 4; ++i) {
        int row = bm + wr * WM + fm * 16 + lhi * 4 + i;
        float v = acc[fm][fn][i] + bv;
        if (act) v = gelu_f(v);
        C[(size_t)row * NSTRIDE + col] = f2b(v);
      }
    }
  }
}

// XCD-swizzled standalone GEMM (dbuf)
template<int BM, int BN, int WM, int WN, int ACT>
__global__ __launch_bounds__(256) void gemm_swz64(
    const unsigned short* __restrict__ A, const unsigned short* __restrict__ W,
    const float* __restrict__ bias, unsigned short* __restrict__ C,
    int M, int NSTRIDE, int K, int nbN) {
  __shared__ __align__(16) unsigned short As[2 * BM * 64];
  __shared__ __align__(16) unsigned short Bs[2 * BN * 64];
  int l = xcd_logical(blockIdx.x, gridDim.x);
  int mb = l / nbN, nb = l % nbN;
  f32x4 acc[WM / 16][WN / 16] = {};
  gemm_core<BM, BN, WM, WN>(A, W, K, mb * BM, nb * BN, As, Bs, acc);
  gemm_store<BM, BN, WM, WN>(bias, C, NSTRIDE, ACT != 0, mb * BM, nb * BN, acc);
}

// merged: ATE hidden 256x128 (LN-folded, head-partial epilogue) [0,384)
//        + qkv 128x256 via tokmap [384,654)
//        + Wcomb weight-fold 128x128 [654,690)
//        + asp masked means [690,946)
__global__ __launch_bounds__(512) void dual_gemm_kernel(
    const unsigned short* __restrict__ sbf, const unsigned short* __restrict__ w1b,
    const float* __restrict__ b1, const float2* __restrict__ c12,
    const float2* __restrict__ stats, const float* __restrict__ lng,
    const float* __restrict__ w2, float4* __restrict__ hpart,
    const unsigned short* __restrict__ winb, const float* __restrict__ b_in,
    unsigned short* __restrict__ qkv, const int* __restrict__ tokmap,
    const unsigned short* __restrict__ fusbR, const unsigned short* __restrict__ w_outT,
    unsigned short* __restrict__ Wbig,
    const int* __restrict__ st, const int* __restrict__ en,
    unsigned short* __restrict__ comb) {
  __shared__ __align__(16) unsigned short lds[2 * 384 * 64];   // 96 KB dbuf
  if (blockIdx.x < 384) {
    int l = xcd_logical(blockIdx.x, 384);
    int mb = l / 3, nb = l % 3;
    const int bm = mb * 256, bn = nb * 128;
    f32x4 acc[4][4] = {};
    gemm_core<256, 128, 64, 64>(sbf, w1b, 768, bm, bn, lds, lds + 2 * 256 * 64, acc);
    const int lane = threadIdx.x & 63;
    const int wv = threadIdx.x >> 6;
    const int wr = wv >> 1, wc = wv & 1;        // NWC=2
    const int l16 = lane & 15, lhi = lane >> 4;
    float b1v[4], gw2a[4], gw2b[4], c1v[4], c2v[4];
    #pragma unroll
    for (int fn = 0; fn < 4; ++fn) {
      int col = bn + wc * 64 + fn * 16 + l16;
      b1v[fn] = b1[col];
      float2 cc = c12[col];
      c1v[fn] = cc.x; c2v[fn] = cc.y;
      float gg = lng[col];
      gw2a[fn] = gg * w2[col];
      gw2b[fn] = gg * w2[384 + col];
    }
    #pragma unroll
    for (int fm = 0; fm < 4; ++fm) {
      #pragma unroll
      for (int i = 0; i < 4; ++i) {
        int row = bm + wr * 64 + fm * 16 + lhi * 4 + i;
        float2 sr = stats[row];
        float s1 = 0.f, s2 = 0.f, q0 = 0.f, q1 = 0.f;
        #pragma unroll
        for (int fn = 0; fn < 4; ++fn) {
          float h = gelu_f(sr.x * acc[fm][fn][i] - sr.y * c1v[fn] + c2v[fn] + b1v[fn]);
          s1 += h; s2 += h * h;
          q0 += h * gw2a[fn]; q1 += h * gw2b[fn];
        }
        #pragma unroll
        for (int off = 1; off < 16; off <<= 1) {
          s1 += __shfl_xor(s1, off); s2 += __shfl_xor(s2, off);
          q0 += __shfl_xor(q0, off); q1 += __shfl_xor(q1, off);
        }
        if (l16 == 0) hpart[(size_t)row * 6 + nb * 2 + wc] = make_float4(s1, s2, q0, q1);
      }
    }
  } else if (blockIdx.x < 654) {
    int bid = blockIdx.x - 384;
    int l = xcd_logical(bid, 270);
    int mb = l / 9, nb = l % 9;
    f32x4 acc[4][4] = {};
    gemm_core<128, 256, 64, 64>(sbf, winb, 768, mb * 128, nb * 256,
                                lds, lds + 2 * 128 * 64, acc, tokmap);
    gemm_store<128, 256, 64, 64>(b_in, qkv, 2304, false, mb * 128, nb * 256, acc);
  } else if (blockIdx.x < 690) {
    if (threadIdx.x >= 256) return;            // 4-wave tile
    int l = blockIdx.x - 654;
    int mb = l / 6, nb = l % 6;
    f32x4 acc[4][4] = {};
    gemm_core<128, 128, 64, 64>(fusbR, w_outT, 768, mb * 128, nb * 128,
                                lds, lds + 2 * 128 * 64, acc);
    gemm_store<128, 128, 64, 64>(nullptr, Wbig + 768, 1536, false, mb * 128, nb * 128, acc);
  } else {
    // asp masked means -> comb[span][0:768]
    if (threadIdx.x >= 256) return;
    const int tid = threadIdx.x;
    const int span = blockIdx.x - 690;
    int s, e, left, right;
    span_params(st, en, span, s, e, left, right);
    int b = span >> 2;
    int e2 = min(e, s + 8);
    int cnt = e2 - s;
    float inva = (cnt > 0) ? 1.0f / (float)cnt : 0.f;
    for (int c = tid; c < 768; c += 256) {
      float sa = 0.f;
      for (int t = s; t < e2; ++t) sa += b2f(sbf[((size_t)b * 512 + t) * 768 + c]);
      float asp = (cnt > 0) ? sa * inva : b2f(sbf[((size_t)b * 512) * 768 + c]);
      comb[(size_t)span * 1536 + c] = f2b(asp);
    }
  }
}

// ---------------- merged: attention->span-mean (bid<2048) + ATE head finish [2048,2176) --
__global__ __launch_bounds__(256) void finattn_kernel(
    const float4* __restrict__ hpart, const float* __restrict__ lng,
    const float* __restrict__ lnb, const float* __restrict__ w2,
    const float* __restrict__ b2, float* __restrict__ out,
    const unsigned short* __restrict__ qkv, const int* __restrict__ st,
    const int* __restrict__ en, unsigned short* __restrict__ comb) {
  const int tid = threadIdx.x;
  if (blockIdx.x >= 2048) {
    __shared__ float cbuf[16];
    float c1a = 0.f, c1b = 0.f, c2a = 0.f, c2b = 0.f;
    for (int c = tid; c < 384; c += 256) {
      float gg = lng[c], bbv = lnb[c], wa = w2[c], wb = w2[384 + c];
      c1a += gg * wa; c1b += gg * wb;
      c2a += bbv * wa; c2b += bbv * wb;
    }
    wredxor2(c1a, c1b);
    wredxor2(c2a, c2b);
    if ((tid & 63) == 0) {
      int w = tid >> 6;
      cbuf[w * 4] = c1a; cbuf[w * 4 + 1] = c1b;
      cbuf[w * 4 + 2] = c2a; cbuf[w * 4 + 3] = c2b;
    }
    __syncthreads();
    c1a = cbuf[0] + cbuf[4] + cbuf[8] + cbuf[12];
    c1b = cbuf[1] + cbuf[5] + cbuf[9] + cbuf[13];
    c2a = cbuf[2] + cbuf[6] + cbuf[10] + cbuf[14];
    c2b = cbuf[3] + cbuf[7] + cbuf[11] + cbuf[15];
    const int row = (blockIdx.x - 2048) * 256 + tid;
    float S1 = 0.f, S2 = 0.f, D0 = 0.f, D1 = 0.f;
    #pragma unroll
    for (int p = 0; p < 6; ++p) {
      float4 v = hpart[(size_t)row * 6 + p];
      S1 += v.x; S2 += v.y; D0 += v.z; D1 += v.w;
    }
    float mu = S1 * (1.f / 384.f);
    float rstd = rsqrtf(S2 * (1.f / 384.f) - mu * mu + 1e-5f);
    out[(size_t)row * 2]     = rstd * (D0 - mu * c1a) + c2a + b2[0];
    out[(size_t)row * 2 + 1] = rstd * (D1 - mu * c1b) + c2b + b2[1];
    return;
  }
  __shared__ float qs[15][96], ks[15][96], vs[15][96];
  __shared__ float sc[15][16];
  __shared__ float wsum[15];
  const int span = blockIdx.x >> 3, hh = blockIdx.x & 7;
  int s, e, left, right;
  span_params(st, en, span, s, e, left, right);
  const int nv = right - left;
  const int r0 = span * 15;
  const float scale = 0.10206207261596576f;   // 1/sqrt(96)
  if (tid < 180) {
    int w = tid / 12, dp = tid % 12, d = dp * 8;
    const unsigned short* rowp = qkv + (size_t)(r0 + w) * 2304 + hh * 96 + d;
    bf16x8 qv = *reinterpret_cast<const bf16x8*>(rowp);
    bf16x8 kv = *reinterpret_cast<const bf16x8*>(rowp + 768);
    bf16x8 vv = *reinterpret_cast<const bf16x8*>(rowp + 1536);
    #pragma unroll
    for (int j = 0; j < 8; ++j) {
      qs[w][d + j] = b2f((unsigned short)qv[j]) * scale;
      ks[w][d + j] = b2f((unsigned short)kv[j]);
      vs[w][d + j] = b2f((unsigned short)vv[j]);
    }
  }
  __syncthreads();
  if (tid < 225) {
    int i = tid / 15, j = tid % 15;
    float a = 0.f;
    #pragma unroll
    for (int d = 0; d < 96; ++d) a += qs[i][d] * ks[j][d];
    sc[i][j] = (j < nv) ? a : -3.402823466e38f;
  }
  __syncthreads();
  // wave-parallel softmax: thread (i,j) = (tid>>4, tid&15); 16-lane butterflies
  if (tid < 240) {
    int i = tid >> 4, j = tid & 15;
    float v = (j < 15) ? sc[i][j] : -3.402823466e38f;
    float m = v;
    #pragma unroll
    for (int off = 8; off; off >>= 1) m = fmaxf(m, __shfl_xor(m, off, 16));
    float ex = expf(v - m);          // -inf -> 0
    float ssum = ex;
    #pragma unroll
    for (int off = 8; off; off >>= 1) ssum += __shfl_xor(ssum, off, 16);
    if (j < 15) sc[i][j] = ex / ssum;
  }
  __syncthreads();
  if (tid < 15) {
    int j = tid;
    float a = 0.f;
    for (int i = 0; i < nv; ++i) a += sc[i][j];
    wsum[j] = a;
  }
  __syncthreads();
  if (tid < 96) {
    int d = tid;
    float r = 0.f;
    #pragma unroll
    for (int j = 0; j < 15; ++j) r += wsum[j] * vs[j][d];
    comb[(size_t)span * 1536 + 768 + hh * 96 + d] = f2b(r / (float)nv);
  }
}

// ---------------- APC all-in-one ----------------
__global__ __launch_bounds__(256) void apc_all_kernel(
    const unsigned short* __restrict__ fused, const float* __restrict__ g,
    const float* __restrict__ bb, const unsigned short* __restrict__ senb,
    const float* __restrict__ b1, const float* __restrict__ lng,
    const float* __restrict__ lnb, const float* __restrict__ w2,
    const float* __restrict__ b2, float* __restrict__ out) {
  const int b = blockIdx.x, tid = threadIdx.x;
  __shared__ float xs[768];
  __shared__ float hs[384];
  float v[3];
  #pragma unroll
  for (int j = 0; j < 3; ++j) {
    int c = tid + j * 256;
    float a = 0.f;
    #pragma unroll
    for (int n = 0; n < 4; ++n) a += b2f(fused[((size_t)(b * 4 + n)) * 768 + c]);
    v[j] = 0.25f * a;
  }
  float s = v[0] + v[1] + v[2];
  float q = v[0] * v[0] + v[1] * v[1] + v[2] * v[2];
  breduce2<4>(s, q);
  float mean = s * (1.f / 768.f);
  float rstd = rsqrtf(q * (1.f / 768.f) - mean * mean + 1e-5f);
  #pragma unroll
  for (int j = 0; j < 3; ++j) {
    int c = tid + j * 256;
    xs[c] = (v[j] - mean) * rstd * g[c] + bb[c];
  }
  __syncthreads();
  for (int j = tid; j < 384; j += 256) {
    const bf16x8* wrp = reinterpret_cast<const bf16x8*>(senb + (size_t)j * 768);
    float dot = 0.f;
    #pragma unroll 4
    for (int k8 = 0; k8 < 96; ++k8) {
      bf16x8 wv = wrp[k8];
      #pragma unroll
      for (int u = 0; u < 8; ++u) dot += xs[k8 * 8 + u] * b2f((unsigned short)wv[u]);
    }
    hs[j] = gelu_f(dot + b1[j]);
  }
  __syncthreads();
  s = 0.f; q = 0.f;
  for (int j = tid; j < 384; j += 256) { float h = hs[j]; s += h; q += h * h; }
  breduce2<4>(s, q);
  mean = s * (1.f / 384.f);
  rstd = rsqrtf(q * (1.f / 384.f) - mean * mean + 1e-5f);
  float p0 = 0.f, p1 = 0.f;
  for (int j = tid; j < 384; j += 256) {
    float hl = (hs[j] - mean) * rstd * lng[j] + lnb[j];
    p0 += hl * w2[j];
    p1 += hl * w2[384 + j];
  }
  breduce2<4>(p0, p1);
  if (tid == 0) {
    out[b * 2]     = p0 + b2[0];
    out[b * 2 + 1] = p1 + b2[1];
  }
}

extern "C" void kernel_launch(void* const* d_in, const int* in_sizes, int n_in,
                              void* d_out, int out_size, void* d_ws, size_t ws_size,
                              hipStream_t stream) {
  const float* seq    = (const float*)d_in[0];
  const int*   st     = (const int*)d_in[1];
  const int*   en     = (const int*)d_in[2];
  const float* ate_g  = (const float*)d_in[3];
  const float* ate_b  = (const float*)d_in[4];
  const float* apc_g  = (const float*)d_in[5];
  const float* apc_b  = (const float*)d_in[6];
  const float* w_in   = (const float*)d_in[7];
  const float* b_in   = (const float*)d_in[8];
  const float* w_out  = (const float*)d_in[9];
  const float* b_out  = (const float*)d_in[10];
  const float* fus_w  = (const float*)d_in[11];
  const float* fus_b  = (const float*)d_in[12];
  const float* asp_w1 = (const float*)d_in[13];
  const float* asp_b1 = (const float*)d_in[14];
  const float* asp_lng= (const float*)d_in[15];
  const float* asp_lnb= (const float*)d_in[16];
  const float* asp_w2 = (const float*)d_in[17];
  const float* asp_b2 = (const float*)d_in[18];
  const float* sen_w1 = (const float*)d_in[19];
  const float* sen_b1 = (const float*)d_in[20];
  const float* sen_lng= (const float*)d_in[21];
  const float* sen_lnb= (const float*)d_in[22];
  const float* sen_w2 = (const float*)d_in[23];
  const float* sen_b2 = (const float*)d_in[24];
  float* out = (float*)d_out;

  char* wsb = (char*)d_ws;
  unsigned short* sbf   = (unsigned short*)(wsb + 0);            // 32768x768 bf16
  float2*        stats  = (float2*)(wsb + 50331648);             // 32768 x float2
  float2*        c12    = (float2*)(wsb + 50593792);             // 384 x float2
  int*           tokmap = (int*)(wsb + 50596864);                // 3840 ints
  unsigned short* qkvb  = (unsigned short*)(wsb + 50612224);     // 3840x2304
  unsigned short* comb  = (unsigned short*)(wsb + 68306944);     // 256x1536 [asp|cavg]
  unsigned short* fusO  = (unsigned short*)(wsb + 69093376);     // 256x768
  float4*        hpart  = (float4*)(wsb + 69486592);             // 32768x6 float4
  const size_t off_w = 72632320;
  unsigned short* w1b   = (unsigned short*)(wsb + off_w);              // 384x768 (g-scaled)
  unsigned short* winb  = (unsigned short*)(wsb + off_w + 589824);     // 2304x768
  unsigned short* w_outT= (unsigned short*)(wsb + off_w + 4128768);    // 768x768 transposed
  unsigned short* Wbig  = (unsigned short*)(wsb + off_w + 5308416);    // 768x1536 [fuswL|Wcomb]
  unsigned short* fusbR = (unsigned short*)(wsb + off_w + 7667712);    // 768x768
  unsigned short* senb  = (unsigned short*)(wsb + off_w + 8847360);    // 384x768
  float*         bias2  = (float*)(wsb + off_w + 9437184);            // 768 floats

  // 1) prep
  prep_kernel<<<12033, 256, 0, stream>>>(asp_w1, w_in, w_out, fus_w, sen_w1,
                                         fus_b, b_out,
                                         w1b, winb, Wbig, fusbR, senb, w_outT, bias2,
                                         seq, ate_g, ate_b, sbf, stats, c12,
                                         st, en, tokmap);
  // 2) ATE hidden GEMM + qkv GEMM + Wcomb fold + asp-means (T3-min pipelined)
  dual_gemm_kernel<<<946, 512, 0, stream>>>(sbf, w1b, asp_b1, c12, stats,
                                            asp_lng, asp_w2, hpart,
                                            winb, b_in, qkvb, tokmap,
                                            fusbR, w_outT, Wbig,
                                            st, en, comb);
  // 3) attention->span-mean (writes comb right half) + ATE head finish
  finattn_kernel<<<2176, 256, 0, stream>>>(hpart, asp_lng, asp_lnb, asp_w2, asp_b2, out,
                                           qkvb, st, en, comb);
  // 4) fusion GEMM: [asp|cavg] @ [fuswL|Wcomb]^T + bias2 -> gelu -> fusO
  gemm_swz64<64, 64, 32, 32, 1><<<48, 256, 0, stream>>>(
      comb, Wbig, bias2, fusO, 256, 768, 1536, 12);
  // 5) APC all-in-one
  apc_all_kernel<<<64, 256, 0, stream>>>(fusO, apc_g, apc_b, senb, sen_b1,
                                         sen_lng, sen_lnb, sen_w2, sen_b2, out + 65536);
}

// Round 19
// 153.108 us; speedup vs baseline: 1.0360x; 1.0360x over previous
//
#include <hip/hip_runtime.h>
#include <math.h>

#define DEVI __device__ __forceinline__

using bf16x8 = __attribute__((ext_vector_type(8))) short;
using f32x4  = __attribute__((ext_vector_type(4))) float;

DEVI float b2f(unsigned short u) {
  union { unsigned int u; float f; } x; x.u = ((unsigned int)u) << 16; return x.f;
}
DEVI unsigned short f2b(float f) {
  union { float f; unsigned int u; } x; x.f = f;
  unsigned int r = (x.u + 0x7fffu + ((x.u >> 16) & 1u)) >> 16;
  return (unsigned short)r;
}
DEVI float gelu_f(float x) { return 0.5f * x * (1.0f + erff(x * 0.70710678118654752440f)); }

DEVI void wredxor2(float& a, float& b) {
  #pragma unroll
  for (int off = 32; off; off >>= 1) {
    a += __shfl_xor(a, off);
    b += __shfl_xor(b, off);
  }
}

template<int NW>
DEVI void breduce2(float& a, float& b) {
  __shared__ float buf[2 * NW];
  int lane = threadIdx.x & 63;
  int w = threadIdx.x >> 6;
  #pragma unroll
  for (int off = 32; off > 0; off >>= 1) {
    a += __shfl_down(a, off);
    b += __shfl_down(b, off);
  }
  if (lane == 0) { buf[w] = a; buf[NW + w] = b; }
  __syncthreads();
  float ra = 0.f, rb = 0.f;
  #pragma unroll
  for (int i = 0; i < NW; ++i) { ra += buf[i]; rb += buf[NW + i]; }
  a = ra; b = rb;
  __syncthreads();
}

DEVI void span_params(const int* st, const int* en, int span,
                      int& s, int& e, int& left, int& right) {
  int s0 = st[span], e0 = en[span];
  s = min(max(s0, 0), 511);
  e = max(s, min(e0, 511));
  left = max(0, s - 3);
  right = min(512, e + 4);
}

// bijective XCD chunk transform (m204)
DEVI int xcd_logical(int bid, int n) {
  int q = n >> 3, r = n & 7;
  int xcd = bid & 7, idx = bid >> 3;
  return (xcd < r ? xcd * (q + 1) : r * (q + 1) + (xcd - r) * q) + idx;
}

// ---------------- fused prep ----------------
__global__ __launch_bounds__(256) void prep_kernel(
    const float* __restrict__ w1, const float* __restrict__ w_in,
    const float* __restrict__ w_out, const float* __restrict__ fus_w,
    const float* __restrict__ sen_w1, const float* __restrict__ fus_b,
    const float* __restrict__ b_out,
    unsigned short* __restrict__ w1b, unsigned short* __restrict__ winb,
    unsigned short* __restrict__ Wbig, unsigned short* __restrict__ fusbR,
    unsigned short* __restrict__ senb, unsigned short* __restrict__ w_outT,
    float* __restrict__ bias2,
    const float* __restrict__ seq, const float* __restrict__ ate_g,
    const float* __restrict__ ate_b, unsigned short* __restrict__ sbf,
    float2* __restrict__ stats, float2* __restrict__ c12,
    const int* __restrict__ st, const int* __restrict__ en,
    int* __restrict__ tokmap) {
  __shared__ unsigned short ldsT[8 * 776];      // 12.4 KB (occupancy-safe)
  const int bid = blockIdx.x, tid = threadIdx.x;
  if (bid < 3456) {
    int i = bid * 256 + tid;
    if (i < 73728) {
      float4 v = reinterpret_cast<const float4*>(w1)[i];
      int k0 = (i * 4) % 768;
      float4 gv = *reinterpret_cast<const float4*>(ate_g + k0);
      ushort4 o;
      o.x = f2b(v.x * gv.x); o.y = f2b(v.y * gv.y);
      o.z = f2b(v.z * gv.z); o.w = f2b(v.w * gv.w);
      reinterpret_cast<ushort4*>(w1b)[i] = o;
      return;
    }
    if (i < 516096) {
      int j = i - 73728;
      float4 v = reinterpret_cast<const float4*>(w_in)[j];
      ushort4 o;
      o.x = f2b(v.x); o.y = f2b(v.y); o.z = f2b(v.z); o.w = f2b(v.w);
      reinterpret_cast<ushort4*>(winb)[j] = o;
      return;
    }
    if (i < 811008) {
      int j = i - 516096;                  // float4 idx in fus_w [768][1536]
      float4 v = reinterpret_cast<const float4*>(fus_w)[j];
      ushort4 o;
      o.x = f2b(v.x); o.y = f2b(v.y); o.z = f2b(v.z); o.w = f2b(v.w);
      int row = j / 384, col4 = j % 384;
      if (col4 < 192)
        reinterpret_cast<ushort4*>(Wbig)[row * 384 + col4] = o;      // left half
      else
        reinterpret_cast<ushort4*>(fusbR)[row * 192 + (col4 - 192)] = o;
      return;
    }
    int j = i - 811008;
    float4 v = reinterpret_cast<const float4*>(sen_w1)[j];
    ushort4 o;
    o.x = f2b(v.x); o.y = f2b(v.y); o.z = f2b(v.z); o.w = f2b(v.w);
    reinterpret_cast<ushort4*>(senb)[j] = o;
  } else if (bid < 11648) {
    const int row = (bid - 3456) * 4 + (tid >> 6);
    const int lane = tid & 63;
    const float4* xr = reinterpret_cast<const float4*>(seq + (size_t)row * 768);
    float4 v[3];
    #pragma unroll
    for (int j = 0; j < 3; ++j) v[j] = xr[j * 64 + lane];
    float s = 0.f, q = 0.f;
    #pragma unroll
    for (int j = 0; j < 3; ++j) {
      s += v[j].x + v[j].y + v[j].z + v[j].w;
      q += v[j].x * v[j].x + v[j].y * v[j].y + v[j].z * v[j].z + v[j].w * v[j].w;
    }
    wredxor2(s, q);
    float mean = s * (1.0f / 768.0f);
    float rstd = rsqrtf(q * (1.0f / 768.0f) - mean * mean + 1e-5f);
    ushort4* orow = reinterpret_cast<ushort4*>(sbf + (size_t)row * 768);
    #pragma unroll
    for (int j = 0; j < 3; ++j) {
      ushort4 o;
      o.x = f2b(v[j].x); o.y = f2b(v[j].y); o.z = f2b(v[j].z); o.w = f2b(v[j].w);
      orow[j * 64 + lane] = o;
    }
    if (lane == 0) stats[row] = make_float2(rstd, rstd * mean);
  } else if (bid < 11744) {
    const int lane = tid & 63;
    const int j = (bid - 11648) * 4 + (tid >> 6);
    const float4* wr = reinterpret_cast<const float4*>(w1 + (size_t)j * 768);
    const float4* gp = reinterpret_cast<const float4*>(ate_g);
    const float4* bp = reinterpret_cast<const float4*>(ate_b);
    float a = 0.f, bsum = 0.f;
    #pragma unroll
    for (int i = 0; i < 3; ++i) {
      float4 wv = wr[i * 64 + lane];
      float4 gv = gp[i * 64 + lane];
      float4 bv = bp[i * 64 + lane];
      a    += gv.x * wv.x + gv.y * wv.y + gv.z * wv.z + gv.w * wv.w;
      bsum += bv.x * wv.x + bv.y * wv.y + bv.z * wv.z + bv.w * wv.w;
    }
    wredxor2(a, bsum);
    if (lane == 0) c12[j] = make_float2(a, bsum);
  } else if (bid < 11936) {
    // bias2[o] = fus_b[o] + sum_k fus_w[o][768+k] * b_out[k]
    const int lane = tid & 63;
    const int o = (bid - 11744) * 4 + (tid >> 6);
    const float4* wr = reinterpret_cast<const float4*>(fus_w + (size_t)o * 1536 + 768);
    const float4* bp = reinterpret_cast<const float4*>(b_out);
    float a = 0.f, dummy = 0.f;
    #pragma unroll
    for (int i = 0; i < 3; ++i) {
      float4 wv = wr[i * 64 + lane];
      float4 bv = bp[i * 64 + lane];
      a += wv.x * bv.x + wv.y * bv.y + wv.z * bv.z + wv.w * bv.w;
    }
    wredxor2(a, dummy);
    if (lane == 0) bias2[o] = fus_b[o] + a;
  } else if (bid < 12032) {
    // transpose 8-col stripe of w_out -> w_outT rows
    const int c0 = (bid - 11936) * 8;
    #pragma unroll
    for (int it = 0; it < 24; ++it) {
      int j = it * 32 + (tid >> 3);
      int c = tid & 7;
      ldsT[c * 776 + j] = f2b(w_out[(size_t)j * 768 + c0 + c]);
    }
    __syncthreads();
    #pragma unroll
    for (int c = 0; c < 8; ++c) {
      for (int u = tid; u < 768; u += 256)
        w_outT[(size_t)(c0 + c) * 768 + u] = ldsT[c * 776 + u];
    }
  } else {
    for (int i = tid; i < 3840; i += 256) {
      int span = i / 15, w = i % 15;
      int s, e, left, right;
      span_params(st, en, span, s, e, left, right);
      int b = span >> 2;
      tokmap[i] = b * 512 + min(left + w, 511);
    }
  }
}

// ---------------- MFMA bf16 GEMM core: BK=64, XOR-swizzled LDS, single buffer --------
template<int BM, int BN, int WM, int WN>
DEVI void gemm_core(const unsigned short* __restrict__ A,
                    const unsigned short* __restrict__ W,
                    int K, int bm, int bn,
                    unsigned short* As, unsigned short* Bs,
                    f32x4 (&acc)[WM / 16][WN / 16],
                    const int* __restrict__ rowmap = nullptr) {
  constexpr int CA = BM / 8;
  constexpr int CB = BN / 8;
  constexpr int NWC = BN / WN;
  constexpr int WAVES = (BM / WM) * NWC;
  constexpr int CPA = CA / WAVES;
  constexpr int CPB = CB / WAVES;
  constexpr int FM = WM / 16, FN = WN / 16;
  const int tid = threadIdx.x;
  const int lane = tid & 63;
  const int wv = tid >> 6;
  const int wr = wv / NWC, wc = wv % NWC;
  const int l16 = lane & 15, lhi = lane >> 4;
  const int srow = lane >> 3;
  const int scol = 8 * ((lane & 7) ^ srow);

  size_t aoff[CPA], boff[CPB];
  #pragma unroll
  for (int c = 0; c < CPA; ++c) {
    int ar = bm + (wv + c * WAVES) * 8 + srow;
    aoff[c] = (rowmap ? (size_t)rowmap[ar] : (size_t)ar) * K + scol;
  }
  #pragma unroll
  for (int c = 0; c < CPB; ++c)
    boff[c] = (size_t)(bn + (wv + c * WAVES) * 8 + srow) * K + scol;

  const int nt = K / 64;
  for (int t = 0; t < nt; ++t) {
    const int k0 = t * 64;
    #pragma unroll
    for (int c = 0; c < CPA; ++c)
      __builtin_amdgcn_global_load_lds(
          (const __attribute__((address_space(1))) void*)&A[aoff[c] + k0],
          (__attribute__((address_space(3))) void*)&As[(wv + c * WAVES) * 512], 16, 0, 0);
    #pragma unroll
    for (int c = 0; c < CPB; ++c)
      __builtin_amdgcn_global_load_lds(
          (const __attribute__((address_space(1))) void*)&W[boff[c] + k0],
          (__attribute__((address_space(3))) void*)&Bs[(wv + c * WAVES) * 512], 16, 0, 0);
    __syncthreads();
    #pragma unroll
    for (int kk = 0; kk < 2; ++kk) {
      bf16x8 af[FM], bfr[FN];
      #pragma unroll
      for (int fm = 0; fm < FM; ++fm) {
        int r = wr * WM + fm * 16 + l16;
        af[fm] = *reinterpret_cast<const bf16x8*>(&As[r * 64 + ((kk * 32 + lhi * 8) ^ ((r & 7) * 8))]);
      }
      #pragma unroll
      for (int fn = 0; fn < FN; ++fn) {
        int r = wc * WN + fn * 16 + l16;
        bfr[fn] = *reinterpret_cast<const bf16x8*>(&Bs[r * 64 + ((kk * 32 + lhi * 8) ^ ((r & 7) * 8))]);
      }
      __builtin_amdgcn_s_setprio(1);       // T5: favor MFMA wave on mixed-phase CU
      #pragma unroll
      for (int fm = 0; fm < FM; ++fm)
        #pragma unroll
        for (int fn = 0; fn < FN; ++fn)
          acc[fm][fn] = __builtin_amdgcn_mfma_f32_16x16x32_bf16(af[fm], bfr[fn], acc[fm][fn], 0, 0, 0);
      __builtin_amdgcn_s_setprio(0);
    }
    __syncthreads();
  }
}

// standard epilogue: bias (+gelu) -> bf16 store (NSTRIDE = C row stride; bias may be null)
template<int BM, int BN, int WM, int WN>
DEVI void gemm_store(const float* __restrict__ bias, unsigned short* __restrict__ C,
                     int NSTRIDE, bool act, int bm, int bn, f32x4 (&acc)[WM / 16][WN / 16]) {
  constexpr int NWC = BN / WN;
  constexpr int FM = WM / 16, FN = WN / 16;
  const int lane = threadIdx.x & 63;
  const int wv = threadIdx.x >> 6;
  const int wr = wv / NWC, wc = wv % NWC;
  const int l16 = lane & 15, lhi = lane >> 4;
  #pragma unroll
  for (int fm = 0; fm < FM; ++fm) {
    #pragma unroll
    for (int fn = 0; fn < FN; ++fn) {
      int col = bn + wc * WN + fn * 16 + l16;
      float bv = bias ? bias[col] : 0.f;
      #pragma unroll
      for (int i = 0; i < 4; ++i) {
        int row = bm + wr * WM + fm * 16 + lhi * 4 + i;
        float v = acc[fm][fn][i] + bv;
        if (act) v = gelu_f(v);
        C[(size_t)row * NSTRIDE + col] = f2b(v);
      }
    }
  }
}

// XCD-swizzled standalone GEMM
template<int BM, int BN, int WM, int WN, int ACT>
__global__ __launch_bounds__(256) void gemm_swz64(
    const unsigned short* __restrict__ A, const unsigned short* __restrict__ W,
    const float* __restrict__ bias, unsigned short* __restrict__ C,
    int M, int NSTRIDE, int K, int nbN) {
  __shared__ __align__(16) unsigned short As[BM * 64];
  __shared__ __align__(16) unsigned short Bs[BN * 64];
  int l = xcd_logical(blockIdx.x, gridDim.x);
  int mb = l / nbN, nb = l % nbN;
  f32x4 acc[WM / 16][WN / 16] = {};
  gemm_core<BM, BN, WM, WN>(A, W, K, mb * BM, nb * BN, As, Bs, acc);
  gemm_store<BM, BN, WM, WN>(bias, C, NSTRIDE, ACT != 0, mb * BM, nb * BN, acc);
}

// merged: ATE hidden 256x128 (LN-folded, head-partial epilogue) [0,384)
//        + qkv 128x256 via tokmap [384,654)
//        + Wcomb weight-fold 128x128 [654,690)
//        + asp masked means [690,946)
__global__ __launch_bounds__(512) void dual_gemm_kernel(
    const unsigned short* __restrict__ sbf, const unsigned short* __restrict__ w1b,
    const float* __restrict__ b1, const float2* __restrict__ c12,
    const float2* __restrict__ stats, const float* __restrict__ lng,
    const float* __restrict__ w2, float4* __restrict__ hpart,
    const unsigned short* __restrict__ winb, const float* __restrict__ b_in,
    unsigned short* __restrict__ qkv, const int* __restrict__ tokmap,
    const unsigned short* __restrict__ fusbR, const unsigned short* __restrict__ w_outT,
    unsigned short* __restrict__ Wbig,
    const int* __restrict__ st, const int* __restrict__ en,
    unsigned short* __restrict__ comb) {
  __shared__ __align__(16) unsigned short lds[384 * 64];   // 48 KB
  if (blockIdx.x < 384) {
    int l = xcd_logical(blockIdx.x, 384);
    int mb = l / 3, nb = l % 3;
    const int bm = mb * 256, bn = nb * 128;
    f32x4 acc[4][4] = {};
    gemm_core<256, 128, 64, 64>(sbf, w1b, 768, bm, bn, lds, lds + 256 * 64, acc);
    const int lane = threadIdx.x & 63;
    const int wv = threadIdx.x >> 6;
    const int wr = wv >> 1, wc = wv & 1;        // NWC=2
    const int l16 = lane & 15, lhi = lane >> 4;
    float b1v[4], gw2a[4], gw2b[4], c1v[4], c2v[4];
    #pragma unroll
    for (int fn = 0; fn < 4; ++fn) {
      int col = bn + wc * 64 + fn * 16 + l16;
      b1v[fn] = b1[col];
      float2 cc = c12[col];
      c1v[fn] = cc.x; c2v[fn] = cc.y;
      float gg = lng[col];
      gw2a[fn] = gg * w2[col];
      gw2b[fn] = gg * w2[384 + col];
    }
    #pragma unroll
    for (int fm = 0; fm < 4; ++fm) {
      #pragma unroll
      for (int i = 0; i < 4; ++i) {
        int row = bm + wr * 64 + fm * 16 + lhi * 4 + i;
        float2 sr = stats[row];
        float s1 = 0.f, s2 = 0.f, q0 = 0.f, q1 = 0.f;
        #pragma unroll
        for (int fn = 0; fn < 4; ++fn) {
          float h = gelu_f(sr.x * acc[fm][fn][i] - sr.y * c1v[fn] + c2v[fn] + b1v[fn]);
          s1 += h; s2 += h * h;
          q0 += h * gw2a[fn]; q1 += h * gw2b[fn];
        }
        #pragma unroll
        for (int off = 1; off < 16; off <<= 1) {
          s1 += __shfl_xor(s1, off); s2 += __shfl_xor(s2, off);
          q0 += __shfl_xor(q0, off); q1 += __shfl_xor(q1, off);
        }
        if (l16 == 0) hpart[(size_t)row * 6 + nb * 2 + wc] = make_float4(s1, s2, q0, q1);
      }
    }
  } else if (blockIdx.x < 654) {
    int bid = blockIdx.x - 384;
    int l = xcd_logical(bid, 270);
    int mb = l / 9, nb = l % 9;
    f32x4 acc[4][4] = {};
    gemm_core<128, 256, 64, 64>(sbf, winb, 768, mb * 128, nb * 256,
                                lds, lds + 128 * 64, acc, tokmap);
    gemm_store<128, 256, 64, 64>(b_in, qkv, 2304, false, mb * 128, nb * 256, acc);
  } else if (blockIdx.x < 690) {
    if (threadIdx.x >= 256) return;            // 4-wave tile
    int l = blockIdx.x - 654;
    int mb = l / 6, nb = l % 6;
    f32x4 acc[4][4] = {};
    gemm_core<128, 128, 64, 64>(fusbR, w_outT, 768, mb * 128, nb * 128,
                                lds, lds + 128 * 64, acc);
    gemm_store<128, 128, 64, 64>(nullptr, Wbig + 768, 1536, false, mb * 128, nb * 128, acc);
  } else {
    // asp masked means -> comb[span][0:768]
    if (threadIdx.x >= 256) return;
    const int tid = threadIdx.x;
    const int span = blockIdx.x - 690;
    int s, e, left, right;
    span_params(st, en, span, s, e, left, right);
    int b = span >> 2;
    int e2 = min(e, s + 8);
    int cnt = e2 - s;
    float inva = (cnt > 0) ? 1.0f / (float)cnt : 0.f;
    for (int c = tid; c < 768; c += 256) {
      float sa = 0.f;
      for (int t = s; t < e2; ++t) sa += b2f(sbf[((size_t)b * 512 + t) * 768 + c]);
      float asp = (cnt > 0) ? sa * inva : b2f(sbf[((size_t)b * 512) * 768 + c]);
      comb[(size_t)span * 1536 + c] = f2b(asp);
    }
  }
}

// ---------------- merged: attention->span-mean (bid<2048) + ATE head finish [2048,2176) --
__global__ __launch_bounds__(256) void finattn_kernel(
    const float4* __restrict__ hpart, const float* __restrict__ lng,
    const float* __restrict__ lnb, const float* __restrict__ w2,
    const float* __restrict__ b2, float* __restrict__ out,
    const unsigned short* __restrict__ qkv, const int* __restrict__ st,
    const int* __restrict__ en, unsigned short* __restrict__ comb) {
  const int tid = threadIdx.x;
  if (blockIdx.x >= 2048) {
    __shared__ float cbuf[16];
    float c1a = 0.f, c1b = 0.f, c2a = 0.f, c2b = 0.f;
    for (int c = tid; c < 384; c += 256) {
      float gg = lng[c], bbv = lnb[c], wa = w2[c], wb = w2[384 + c];
      c1a += gg * wa; c1b += gg * wb;
      c2a += bbv * wa; c2b += bbv * wb;
    }
    wredxor2(c1a, c1b);
    wredxor2(c2a, c2b);
    if ((tid & 63) == 0) {
      int w = tid >> 6;
      cbuf[w * 4] = c1a; cbuf[w * 4 + 1] = c1b;
      cbuf[w * 4 + 2] = c2a; cbuf[w * 4 + 3] = c2b;
    }
    __syncthreads();
    c1a = cbuf[0] + cbuf[4] + cbuf[8] + cbuf[12];
    c1b = cbuf[1] + cbuf[5] + cbuf[9] + cbuf[13];
    c2a = cbuf[2] + cbuf[6] + cbuf[10] + cbuf[14];
    c2b = cbuf[3] + cbuf[7] + cbuf[11] + cbuf[15];
    const int row = (blockIdx.x - 2048) * 256 + tid;
    float S1 = 0.f, S2 = 0.f, D0 = 0.f, D1 = 0.f;
    #pragma unroll
    for (int p = 0; p < 6; ++p) {
      float4 v = hpart[(size_t)row * 6 + p];
      S1 += v.x; S2 += v.y; D0 += v.z; D1 += v.w;
    }
    float mu = S1 * (1.f / 384.f);
    float rstd = rsqrtf(S2 * (1.f / 384.f) - mu * mu + 1e-5f);
    out[(size_t)row * 2]     = rstd * (D0 - mu * c1a) + c2a + b2[0];
    out[(size_t)row * 2 + 1] = rstd * (D1 - mu * c1b) + c2b + b2[1];
    return;
  }
  __shared__ float qs[15][96], ks[15][96], vs[15][96];
  __shared__ float sc[15][16];
  __shared__ float wsum[15];
  const int span = blockIdx.x >> 3, hh = blockIdx.x & 7;
  int s, e, left, right;
  span_params(st, en, span, s, e, left, right);
  const int nv = right - left;
  const int r0 = span * 15;
  const float scale = 0.10206207261596576f;   // 1/sqrt(96)
  if (tid < 180) {
    int w = tid / 12, dp = tid % 12, d = dp * 8;
    const unsigned short* rowp = qkv + (size_t)(r0 + w) * 2304 + hh * 96 + d;
    bf16x8 qv = *reinterpret_cast<const bf16x8*>(rowp);
    bf16x8 kv = *reinterpret_cast<const bf16x8*>(rowp + 768);
    bf16x8 vv = *reinterpret_cast<const bf16x8*>(rowp + 1536);
    #pragma unroll
    for (int j = 0; j < 8; ++j) {
      qs[w][d + j] = b2f((unsigned short)qv[j]) * scale;
      ks[w][d + j] = b2f((unsigned short)kv[j]);
      vs[w][d + j] = b2f((unsigned short)vv[j]);
    }
  }
  __syncthreads();
  if (tid < 225) {
    int i = tid / 15, j = tid % 15;
    float a = 0.f;
    #pragma unroll
    for (int d = 0; d < 96; ++d) a += qs[i][d] * ks[j][d];
    sc[i][j] = (j < nv) ? a : -3.402823466e38f;
  }
  __syncthreads();
  // wave-parallel softmax: thread (i,j) = (tid>>4, tid&15); 16-lane butterflies
  if (tid < 240) {
    int i = tid >> 4, j = tid & 15;
    float v = (j < 15) ? sc[i][j] : -3.402823466e38f;
    float m = v;
    #pragma unroll
    for (int off = 8; off; off >>= 1) m = fmaxf(m, __shfl_xor(m, off, 16));
    float ex = expf(v - m);          // -inf -> 0
    float ssum = ex;
    #pragma unroll
    for (int off = 8; off; off >>= 1) ssum += __shfl_xor(ssum, off, 16);
    if (j < 15) sc[i][j] = ex / ssum;
  }
  __syncthreads();
  if (tid < 15) {
    int j = tid;
    float a = 0.f;
    for (int i = 0; i < nv; ++i) a += sc[i][j];
    wsum[j] = a;
  }
  __syncthreads();
  if (tid < 96) {
    int d = tid;
    float r = 0.f;
    #pragma unroll
    for (int j = 0; j < 15; ++j) r += wsum[j] * vs[j][d];
    comb[(size_t)span * 1536 + 768 + hh * 96 + d] = f2b(r / (float)nv);
  }
}

// ---------------- APC all-in-one ----------------
__global__ __launch_bounds__(256) void apc_all_kernel(
    const unsigned short* __restrict__ fused, const float* __restrict__ g,
    const float* __restrict__ bb, const unsigned short* __restrict__ senb,
    const float* __restrict__ b1, const float* __restrict__ lng,
    const float* __restrict__ lnb, const float* __restrict__ w2,
    const float* __restrict__ b2, float* __restrict__ out) {
  const int b = blockIdx.x, tid = threadIdx.x;
  __shared__ float xs[768];
  __shared__ float hs[384];
  float v[3];
  #pragma unroll
  for (int j = 0; j < 3; ++j) {
    int c = tid + j * 256;
    float a = 0.f;
    #pragma unroll
    for (int n = 0; n < 4; ++n) a += b2f(fused[((size_t)(b * 4 + n)) * 768 + c]);
    v[j] = 0.25f * a;
  }
  float s = v[0] + v[1] + v[2];
  float q = v[0] * v[0] + v[1] * v[1] + v[2] * v[2];
  breduce2<4>(s, q);
  float mean = s * (1.f / 768.f);
  float rstd = rsqrtf(q * (1.f / 768.f) - mean * mean + 1e-5f);
  #pragma unroll
  for (int j = 0; j < 3; ++j) {
    int c = tid + j * 256;
    xs[c] = (v[j] - mean) * rstd * g[c] + bb[c];
  }
  __syncthreads();
  for (int j = tid; j < 384; j += 256) {
    const bf16x8* wrp = reinterpret_cast<const bf16x8*>(senb + (size_t)j * 768);
    float dot = 0.f;
    #pragma unroll 4
    for (int k8 = 0; k8 < 96; ++k8) {
      bf16x8 wv = wrp[k8];
      #pragma unroll
      for (int u = 0; u < 8; ++u) dot += xs[k8 * 8 + u] * b2f((unsigned short)wv[u]);
    }
    hs[j] = gelu_f(dot + b1[j]);
  }
  __syncthreads();
  s = 0.f; q = 0.f;
  for (int j = tid; j < 384; j += 256) { float h = hs[j]; s += h; q += h * h; }
  breduce2<4>(s, q);
  mean = s * (1.f / 384.f);
  rstd = rsqrtf(q * (1.f / 384.f) - mean * mean + 1e-5f);
  float p0 = 0.f, p1 = 0.f;
  for (int j = tid; j < 384; j += 256) {
    float hl = (hs[j] - mean) * rstd * lng[j] + lnb[j];
    p0 += hl * w2[j];
    p1 += hl * w2[384 + j];
  }
  breduce2<4>(p0, p1);
  if (tid == 0) {
    out[b * 2]     = p0 + b2[0];
    out[b * 2 + 1] = p1 + b2[1];
  }
}

extern "C" void kernel_launch(void* const* d_in, const int* in_sizes, int n_in,
                              void* d_out, int out_size, void* d_ws, size_t ws_size,
                              hipStream_t stream) {
  const float* seq    = (const float*)d_in[0];
  const int*   st     = (const int*)d_in[1];
  const int*   en     = (const int*)d_in[2];
  const float* ate_g  = (const float*)d_in[3];
  const float* ate_b  = (const float*)d_in[4];
  const float* apc_g  = (const float*)d_in[5];
  const float* apc_b  = (const float*)d_in[6];
  const float* w_in   = (const float*)d_in[7];
  const float* b_in   = (const float*)d_in[8];
  const float* w_out  = (const float*)d_in[9];
  const float* b_out  = (const float*)d_in[10];
  const float* fus_w  = (const float*)d_in[11];
  const float* fus_b  = (const float*)d_in[12];
  const float* asp_w1 = (const float*)d_in[13];
  const float* asp_b1 = (const float*)d_in[14];
  const float* asp_lng= (const float*)d_in[15];
  const float* asp_lnb= (const float*)d_in[16];
  const float* asp_w2 = (const float*)d_in[17];
  const float* asp_b2 = (const float*)d_in[18];
  const float* sen_w1 = (const float*)d_in[19];
  const float* sen_b1 = (const float*)d_in[20];
  const float* sen_lng= (const float*)d_in[21];
  const float* sen_lnb= (const float*)d_in[22];
  const float* sen_w2 = (const float*)d_in[23];
  const float* sen_b2 = (const float*)d_in[24];
  float* out = (float*)d_out;

  char* wsb = (char*)d_ws;
  unsigned short* sbf   = (unsigned short*)(wsb + 0);            // 32768x768 bf16
  float2*        stats  = (float2*)(wsb + 50331648);             // 32768 x float2
  float2*        c12    = (float2*)(wsb + 50593792);             // 384 x float2
  int*           tokmap = (int*)(wsb + 50596864);                // 3840 ints
  unsigned short* qkvb  = (unsigned short*)(wsb + 50612224);     // 3840x2304
  unsigned short* comb  = (unsigned short*)(wsb + 68306944);     // 256x1536 [asp|cavg]
  unsigned short* fusO  = (unsigned short*)(wsb + 69093376);     // 256x768
  float4*        hpart  = (float4*)(wsb + 69486592);             // 32768x6 float4
  const size_t off_w = 72632320;
  unsigned short* w1b   = (unsigned short*)(wsb + off_w);              // 384x768 (g-scaled)
  unsigned short* winb  = (unsigned short*)(wsb + off_w + 589824);     // 2304x768
  unsigned short* w_outT= (unsigned short*)(wsb + off_w + 4128768);    // 768x768 transposed
  unsigned short* Wbig  = (unsigned short*)(wsb + off_w + 5308416);    // 768x1536 [fuswL|Wcomb]
  unsigned short* fusbR = (unsigned short*)(wsb + off_w + 7667712);    // 768x768
  unsigned short* senb  = (unsigned short*)(wsb + off_w + 8847360);    // 384x768
  float*         bias2  = (float*)(wsb + off_w + 9437184);            // 768 floats

  // 1) prep
  prep_kernel<<<12033, 256, 0, stream>>>(asp_w1, w_in, w_out, fus_w, sen_w1,
                                         fus_b, b_out,
                                         w1b, winb, Wbig, fusbR, senb, w_outT, bias2,
                                         seq, ate_g, ate_b, sbf, stats, c12,
                                         st, en, tokmap);
  // 2) ATE hidden GEMM + qkv GEMM + Wcomb fold + asp-means
  dual_gemm_kernel<<<946, 512, 0, stream>>>(sbf, w1b, asp_b1, c12, stats,
                                            asp_lng, asp_w2, hpart,
                                            winb, b_in, qkvb, tokmap,
                                            fusbR, w_outT, Wbig,
                                            st, en, comb);
  // 3) attention->span-mean (writes comb right half) + ATE head finish
  finattn_kernel<<<2176, 256, 0, stream>>>(hpart, asp_lng, asp_lnb, asp_w2, asp_b2, out,
                                           qkvb, st, en, comb);
  // 4) fusion GEMM: [asp|cavg] @ [fuswL|Wcomb]^T + bias2 -> gelu -> fusO
  gemm_swz64<64, 64, 32, 32, 1><<<48, 256, 0, stream>>>(
      comb, Wbig, bias2, fusO, 256, 768, 1536, 12);
  // 5) APC all-in-one
  apc_all_kernel<<<64, 256, 0, stream>>>(fusO, apc_g, apc_b, senb, sen_b1,
                                         sen_lng, sen_lnb, sen_w2, sen_b2, out + 65536);
}